// Round 1
// baseline (446.869 us; speedup 1.0000x reference)
//
#include <hip/hip_runtime.h>

// Problem constants
constexpr int   FRAMES   = 128 * 1024;   // B*T
constexpr int   NB       = 50;           // bones (== joints)
constexpr int   FRAME_F  = 150;          // floats per frame
constexpr float TINY     = 1.17549435e-38f;  // jnp.finfo(f32).tiny
// final = 0.1 * (sum_abs + 0.1*sum_sq) / (FRAMES*150)
constexpr float SCALE    = 0.1f / (float)(FRAMES * FRAME_F);

__global__ void zero_out_kernel(float* out) { out[0] = 0.0f; }

__global__ __launch_bounds__(256) void bone_loss_kernel(
    const float* __restrict__ preds,
    const float* __restrict__ targets,
    float* __restrict__ out)
{
    const int g     = blockIdx.x * blockDim.x + threadIdx.x;   // [0, FRAMES*NB)
    const int frame = g / NB;
    const int bone  = g - frame * NB;
    const int jb    = (bone == NB - 1) ? 0 : bone + 1;         // (bone+1) % 50

    const int baseI = frame * FRAME_F + bone * 3;
    const int baseJ = frame * FRAME_F + jb * 3;

    // loads: joint i and joint j for both arrays
    const float p0 = preds[baseI],   p1 = preds[baseI+1],   p2 = preds[baseI+2];
    const float q0 = preds[baseJ],   q1 = preds[baseJ+1],   q2 = preds[baseJ+2];
    const float t0 = targets[baseI], t1 = targets[baseI+1], t2 = targets[baseI+2];
    const float u0 = targets[baseJ], u1 = targets[baseJ+1], u2 = targets[baseJ+2];

    // masks (targets*mask == targets identically; only preds needs masking)
    const float m0 = (t0 != 0.0f) ? 1.0f : 0.0f;
    const float m1 = (t1 != 0.0f) ? 1.0f : 0.0f;
    const float m2 = (t2 != 0.0f) ? 1.0f : 0.0f;
    const float n0 = (u0 != 0.0f) ? 1.0f : 0.0f;
    const float n1 = (u1 != 0.0f) ? 1.0f : 0.0f;
    const float n2 = (u2 != 0.0f) ? 1.0f : 0.0f;

    const float pm0 = p0 * m0, pm1 = p1 * m1, pm2 = p2 * m2;
    const float qm0 = q0 * n0, qm1 = q1 * n1, qm2 = q2 * n2;

    // |p*mask - t*mask| over this thread's owned joint (joint i)
    const float ab = fabsf(pm0 - t0) + fabsf(pm1 - t1) + fabsf(pm2 - t2);

    // bone diffs
    const float pd0 = pm0 - qm0, pd1 = pm1 - qm1, pd2 = pm2 - qm2;
    const float td0 = t0  - u0,  td1 = t1  - u1,  td2 = t2  - u2;

    const float plen = sqrtf(pd0*pd0 + pd1*pd1 + pd2*pd2);
    const float tlen = sqrtf(td0*td0 + td1*td1 + td2*td2);
    const float pri  = 1.0f / (plen + TINY);
    const float tri  = 1.0f / (tlen + TINY);

    // direction terms, re-masked with joint-i mask (mask[:,:,:150] slice)
    const float d0 = pd0 * pri * m0 - td0 * tri * m0;
    const float d1 = pd1 * pri * m1 - td1 * tri * m1;
    const float d2 = pd2 * pri * m2 - td2 * tri * m2;

    const float sq = d0*d0 + d1*d1 + d2*d2;

    float v = ab + 0.1f * sq;

    // wave64 shuffle reduce
    #pragma unroll
    for (int off = 32; off > 0; off >>= 1)
        v += __shfl_down(v, off, 64);

    __shared__ float ws[4];
    const int lane = threadIdx.x & 63;
    const int wid  = threadIdx.x >> 6;
    if (lane == 0) ws[wid] = v;
    __syncthreads();
    if (threadIdx.x == 0) {
        const float s = ws[0] + ws[1] + ws[2] + ws[3];
        atomicAdd(out, s * SCALE);
    }
}

extern "C" void kernel_launch(void* const* d_in, const int* in_sizes, int n_in,
                              void* d_out, int out_size, void* d_ws, size_t ws_size,
                              hipStream_t stream) {
    const float* preds   = (const float*)d_in[0];
    const float* targets = (const float*)d_in[1];
    float* out = (float*)d_out;

    zero_out_kernel<<<1, 1, 0, stream>>>(out);

    const int total  = FRAMES * NB;          // 6,553,600 threads, one per bone
    const int block  = 256;
    const int grid   = total / block;        // 25,600 blocks (exact)
    bone_loss_kernel<<<grid, block, 0, stream>>>(preds, targets, out);
}

// Round 2
// 180.204 us; speedup vs baseline: 2.4798x; 2.4798x over previous
//
#include <hip/hip_runtime.h>

// Problem constants
constexpr int   FRAMES   = 128 * 1024;   // B*T
constexpr int   NB       = 50;           // bones (== joints)
constexpr int   FRAME_F  = 150;          // floats per frame
constexpr float TINY     = 1.17549435e-38f;  // jnp.finfo(f32).tiny
// final = 0.1 * (sum_abs + 0.1*sum_sq) / (FRAMES*150)
constexpr float SCALE    = 0.1f / (float)(FRAMES * FRAME_F);

constexpr int FPB   = 32;                // frames per block
constexpr int FLTS  = FPB * FRAME_F;     // 4800 floats per array per block
constexpr int VECS  = FLTS / 4;          // 1200 float4
constexpr int NBLK  = FRAMES / FPB;      // 4096 blocks
constexpr int TASKS = FPB * NB;          // 1600 bone tasks per block

__global__ __launch_bounds__(256) void bone_loss_main(
    const float* __restrict__ preds,
    const float* __restrict__ targets,
    float* __restrict__ partials)
{
    __shared__ float4 sp4[VECS];
    __shared__ float4 st4[VECS];
    float* sp = (float*)sp4;
    float* st = (float*)st4;

    // ---- stage 32 frames of both arrays, fully coalesced float4 ----
    const long base = (long)blockIdx.x * FLTS;
    const float4* gp = (const float4*)(preds + base);
    const float4* gt = (const float4*)(targets + base);
    #pragma unroll
    for (int i = threadIdx.x; i < VECS; i += 256) {
        sp4[i] = gp[i];
        st4[i] = gt[i];
    }
    __syncthreads();

    // ---- compute: one bone task per loop iteration ----
    float acc = 0.0f;
    for (int t = threadIdx.x; t < TASKS; t += 256) {
        const int f  = t / NB;
        const int b  = t - f * NB;
        const int jb = (b == NB - 1) ? 0 : b + 1;
        const int bi = f * FRAME_F + b * 3;
        const int bj = f * FRAME_F + jb * 3;

        const float p0 = sp[bi],   p1 = sp[bi+1], p2 = sp[bi+2];
        const float q0 = sp[bj],   q1 = sp[bj+1], q2 = sp[bj+2];
        const float t0 = st[bi],   t1 = st[bi+1], t2 = st[bi+2];
        const float u0 = st[bj],   u1 = st[bj+1], u2 = st[bj+2];

        // mask: targets*mask == targets; only preds needs masking
        const float m0 = (t0 != 0.0f) ? 1.0f : 0.0f;
        const float m1 = (t1 != 0.0f) ? 1.0f : 0.0f;
        const float m2 = (t2 != 0.0f) ? 1.0f : 0.0f;
        const float n0 = (u0 != 0.0f) ? 1.0f : 0.0f;
        const float n1 = (u1 != 0.0f) ? 1.0f : 0.0f;
        const float n2 = (u2 != 0.0f) ? 1.0f : 0.0f;

        const float pm0 = p0 * m0, pm1 = p1 * m1, pm2 = p2 * m2;
        const float qm0 = q0 * n0, qm1 = q1 * n1, qm2 = q2 * n2;

        // L1 term over this thread's owned joint (joint b)
        const float ab = fabsf(pm0 - t0) + fabsf(pm1 - t1) + fabsf(pm2 - t2);

        // bone diffs
        const float pd0 = pm0 - qm0, pd1 = pm1 - qm1, pd2 = pm2 - qm2;
        const float td0 = t0  - u0,  td1 = t1  - u1,  td2 = t2  - u2;

        const float plen = sqrtf(pd0*pd0 + pd1*pd1 + pd2*pd2);
        const float tlen = sqrtf(td0*td0 + td1*td1 + td2*td2);
        const float pri  = 1.0f / (plen + TINY);
        const float tri  = 1.0f / (tlen + TINY);

        const float d0 = pd0 * pri * m0 - td0 * tri * m0;
        const float d1 = pd1 * pri * m1 - td1 * tri * m1;
        const float d2 = pd2 * pri * m2 - td2 * tri * m2;

        acc += ab + 0.1f * (d0*d0 + d1*d1 + d2*d2);
    }

    // ---- block reduction ----
    #pragma unroll
    for (int off = 32; off > 0; off >>= 1)
        acc += __shfl_down(acc, off, 64);

    __shared__ float ws[4];
    const int lane = threadIdx.x & 63;
    const int wid  = threadIdx.x >> 6;
    if (lane == 0) ws[wid] = acc;
    __syncthreads();
    if (threadIdx.x == 0)
        partials[blockIdx.x] = ws[0] + ws[1] + ws[2] + ws[3];
}

__global__ __launch_bounds__(256) void bone_loss_finish(
    const float* __restrict__ partials,
    float* __restrict__ out)
{
    float v = 0.0f;
    for (int i = threadIdx.x; i < NBLK; i += 256)
        v += partials[i];

    #pragma unroll
    for (int off = 32; off > 0; off >>= 1)
        v += __shfl_down(v, off, 64);

    __shared__ float ws[4];
    const int lane = threadIdx.x & 63;
    const int wid  = threadIdx.x >> 6;
    if (lane == 0) ws[wid] = v;
    __syncthreads();
    if (threadIdx.x == 0)
        out[0] = (ws[0] + ws[1] + ws[2] + ws[3]) * SCALE;
}

extern "C" void kernel_launch(void* const* d_in, const int* in_sizes, int n_in,
                              void* d_out, int out_size, void* d_ws, size_t ws_size,
                              hipStream_t stream) {
    const float* preds   = (const float*)d_in[0];
    const float* targets = (const float*)d_in[1];
    float* out      = (float*)d_out;
    float* partials = (float*)d_ws;       // NBLK floats = 16 KB

    bone_loss_main<<<NBLK, 256, 0, stream>>>(preds, targets, partials);
    bone_loss_finish<<<1, 256, 0, stream>>>(partials, out);
}

// Round 3
// 175.618 us; speedup vs baseline: 2.5446x; 1.0261x over previous
//
#include <hip/hip_runtime.h>

// Problem constants
constexpr int   FRAMES   = 128 * 1024;   // B*T = 131072
constexpr int   NB       = 50;           // bones (== joints)
constexpr int   FRAME_F  = 150;          // floats per frame
// final = 0.1 * (sum_abs + 0.1*sum_sq) / (FRAMES*150)
constexpr float SCALE    = 0.1f / (float)(FRAMES * FRAME_F);

constexpr int FPW    = 16;                    // frames per wave
constexpr int NWAVES = FRAMES / FPW;          // 8192 waves
constexpr int BLOCK  = 256;                   // 4 waves/block
constexpr int NBLK   = NWAVES * 64 / BLOCK;   // 2048 blocks

__global__ __launch_bounds__(256) void bone_loss_main(
    const float* __restrict__ preds,
    const float* __restrict__ targets,
    float* __restrict__ partials)
{
    const int gid   = blockIdx.x * BLOCK + threadIdx.x;
    const int wave  = gid >> 6;
    const int lane  = threadIdx.x & 63;
    const bool act  = lane < NB;
    const int  jcl  = act ? lane : (NB - 1);          // clamp inactive lanes to a valid joint
    const int  sidx = (lane >= NB - 1) ? lane - (NB - 1) : lane + 1;  // (lane+1)%50 for active

    const long fbase = (long)wave * FPW;
    const float* pp = preds   + fbase * FRAME_F + jcl * 3;
    const float* tp = targets + fbase * FRAME_F + jcl * 3;

    float acc = 0.0f;

    // prime first frame (compiler fuses the 3 contiguous loads into dwordx3)
    float p0 = pp[0], p1 = pp[1], p2 = pp[2];
    float t0 = tp[0], t1 = tp[1], t2 = tp[2];

    #pragma unroll
    for (int i = 0; i < FPW; ++i) {
        // ---- prefetch next frame before consuming current ----
        float np0 = 0.f, np1 = 0.f, np2 = 0.f, nt0 = 0.f, nt1 = 0.f, nt2 = 0.f;
        if (i + 1 < FPW) {
            const float* npp = pp + (i + 1) * FRAME_F;
            const float* ntp = tp + (i + 1) * FRAME_F;
            np0 = npp[0]; np1 = npp[1]; np2 = npp[2];
            nt0 = ntp[0]; nt1 = ntp[1]; nt2 = ntp[2];
        }

        // ---- masks: targets*mask == targets identically; mask preds only ----
        const float m0 = (t0 != 0.0f) ? 1.0f : 0.0f;
        const float m1 = (t1 != 0.0f) ? 1.0f : 0.0f;
        const float m2 = (t2 != 0.0f) ? 1.0f : 0.0f;
        const float pm0 = p0 * m0, pm1 = p1 * m1, pm2 = p2 * m2;

        // L1 term over this lane's owned joint
        const float ab = fabsf(pm0 - t0) + fabsf(pm1 - t1) + fabsf(pm2 - t2);

        // neighbor joint (b+1 mod 50) via cross-lane: neighbor's masked-pred IS qm, raw t IS u
        const float qm0 = __shfl(pm0, sidx, 64);
        const float qm1 = __shfl(pm1, sidx, 64);
        const float qm2 = __shfl(pm2, sidx, 64);
        const float u0  = __shfl(t0,  sidx, 64);
        const float u1  = __shfl(t1,  sidx, 64);
        const float u2  = __shfl(t2,  sidx, 64);

        const float pd0 = pm0 - qm0, pd1 = pm1 - qm1, pd2 = pm2 - qm2;
        const float td0 = t0  - u0,  td1 = t1  - u1,  td2 = t2  - u2;

        const float pl2 = pd0*pd0 + pd1*pd1 + pd2*pd2;
        const float tl2 = td0*td0 + td1*td1 + td2*td2;
        // 1/(len+tiny): rsq approximation (rel err ~1e-7, irrelevant to a mean), zero-guarded
        const float pri = (pl2 > 0.0f) ? __builtin_amdgcn_rsqf(pl2) : 0.0f;
        const float tri = (tl2 > 0.0f) ? __builtin_amdgcn_rsqf(tl2) : 0.0f;

        const float d0 = pd0 * pri - td0 * tri;
        const float d1 = pd1 * pri - td1 * tri;
        const float d2 = pd2 * pri - td2 * tri;
        const float sq = m0*d0*d0 + m1*d1*d1 + m2*d2*d2;   // re-mask (mask[:, :, :150] slice)

        acc += act ? (ab + 0.1f * sq) : 0.0f;

        p0 = np0; p1 = np1; p2 = np2;
        t0 = nt0; t1 = nt1; t2 = nt2;
    }

    // ---- block reduction ----
    #pragma unroll
    for (int off = 32; off > 0; off >>= 1)
        acc += __shfl_down(acc, off, 64);

    __shared__ float ws[4];
    const int wid = threadIdx.x >> 6;
    if ((threadIdx.x & 63) == 0) ws[wid] = acc;
    __syncthreads();
    if (threadIdx.x == 0)
        partials[blockIdx.x] = ws[0] + ws[1] + ws[2] + ws[3];
}

__global__ __launch_bounds__(256) void bone_loss_finish(
    const float* __restrict__ partials,
    float* __restrict__ out)
{
    float v = 0.0f;
    for (int i = threadIdx.x; i < NBLK; i += 256)
        v += partials[i];

    #pragma unroll
    for (int off = 32; off > 0; off >>= 1)
        v += __shfl_down(v, off, 64);

    __shared__ float ws[4];
    const int wid = threadIdx.x >> 6;
    if ((threadIdx.x & 63) == 0) ws[wid] = v;
    __syncthreads();
    if (threadIdx.x == 0)
        out[0] = (ws[0] + ws[1] + ws[2] + ws[3]) * SCALE;
}

extern "C" void kernel_launch(void* const* d_in, const int* in_sizes, int n_in,
                              void* d_out, int out_size, void* d_ws, size_t ws_size,
                              hipStream_t stream) {
    const float* preds   = (const float*)d_in[0];
    const float* targets = (const float*)d_in[1];
    float* out      = (float*)d_out;
    float* partials = (float*)d_ws;       // NBLK floats = 8 KB

    bone_loss_main<<<NBLK, BLOCK, 0, stream>>>(preds, targets, partials);
    bone_loss_finish<<<1, 256, 0, stream>>>(partials, out);
}